// Round 6
// baseline (28.833 us; speedup 1.0000x reference)
//
#include <hip/hip_runtime.h>

#define SN 128
#define SPK 512
#define CAP 528   // max compacted entries per (sample, octant): <=518 + 2 pads

constexpr float GMIN  = 0.1f;
constexpr float PFRAC = 0.3f;
constexpr float GMAX  = 1.0f;

// Lazy-decay + per-octant compacted event lists (built once, applied by 1024 blocks).
// State per cell: a = (v - GMIN) / C(n), C(n) = exp((ts0 - ts[n])/TAU)
//   => v(n) = C(n)*a + GMIN, zero per-step work.
// Spike touch at step n: a' = (1-PFRAC)*a + PFRAC*(GMAX-GMIN)/C(n).
//
// Entry (uint4): .x = meta, .y = bits(C), .z = bits(0.27/C), .w unused
// meta: bits 3-6 y>>3 | bits 7-13 x | bit 14 p | bit 15 owner-valid |
//       bits 16-19 jidx ((x&1)<<3 | (y&7)) | bits 24-26 snap slot | bit 31 snap flag
// Owner test vs mypatO=((p<<14)|(x_even<<7)|(yc<<3)|0x8000): (meta & 0xFF78)==mypatO.
// Snapshot test: (int)meta < 0.
// Header (uint4 per (s,oct)): .x = count, .y = missing-slot mask (snlast[r]<0).

// ---- Kernel A: one wave per (sample, octant) builds the compacted list ----
__global__ __launch_bounds__(64, 8) void build_kernel(
    const int*   __restrict__ event,   // (SN, SPK, 3)
    const float* __restrict__ ts,      // (SN, SPK)
    const int*   __restrict__ tt,      // (SN, SPK)
    const int*   __restrict__ length,  // (SN,)
    uint4*       __restrict__ hdr,     // (SN*8)
    uint4*       __restrict__ ent)     // (SN*8, CAP)
{
    const int wg   = blockIdx.x;
    const int s    = wg >> 3;
    const int oct  = wg & 7;
    const int p    = oct >> 2;
    const int xc   = oct & 3;
    const int lane = threadIdx.x;      // 0..63

    const int   len = length[s];
    const float ts0 = ts[s * SPK];

    // load the full step sequence into registers (8 rounds of 64)
    int tv[8]; float tsn[8]; int ex[8], ey[8], ep[8];
#pragma unroll
    for (int r8 = 0; r8 < 8; ++r8) {
        int n = r8 * 64 + lane;
        tv[r8]  = tt[s * SPK + n];
        tsn[r8] = ts[s * SPK + n];
        const int* ev = event + (size_t)(s * SPK + n) * 3;
        ex[r8] = ev[0]; ey[r8] = ev[1]; ep[r8] = ev[2];
    }

    // snlast per slot (wave-uniform, via ballots)
    int snl[8];
#pragma unroll
    for (int r = 0; r < 8; ++r) snl[r] = -1;
#pragma unroll
    for (int r8 = 0; r8 < 8; ++r8) {
        int n = r8 * 64 + lane;
#pragma unroll
        for (int r = 0; r < 8; ++r) {
            unsigned long long m = __ballot(n >= 1 && tv[r8] == r);
            if (m) snl[r] = r8 * 64 + 63 - __clzll(m);
        }
    }

    // stable compaction: owner events for this octant + surviving snapshots
    const unsigned long long lmask = (1ull << lane) - 1ull;
    uint4* myent = ent + (size_t)wg * CAP;
    int base = 0;
#pragma unroll
    for (int r8 = 0; r8 < 8; ++r8) {
        int n = r8 * 64 + lane;
        // snl[tv] via static select chain (wave-uniform values, per-lane index)
        int tvv = tv[r8];
        int sl = snl[0];
        sl = (tvv == 1) ? snl[1] : sl;
        sl = (tvv == 2) ? snl[2] : sl;
        sl = (tvv == 3) ? snl[3] : sl;
        sl = (tvv == 4) ? snl[4] : sl;
        sl = (tvv == 5) ? snl[5] : sl;
        sl = (tvv == 6) ? snl[6] : sl;
        sl = (tvv == 7) ? snl[7] : sl;

        bool powner = (n >= 1) && (n < len) && (ep[r8] == p) && ((ex[r8] >> 5) == xc);
        bool psnap  = (n >= 1) && (sl == n);
        bool pred   = powner || psnap;

        unsigned long long mask = __ballot(pred);
        if (pred) {
            int idx  = base + __popcll(mask & lmask);
            float C  = expf((ts0 - tsn[r8]) * 0.01f);          // TAU = 100
            float Cr = (PFRAC * (GMAX - GMIN)) / C;
            unsigned mw = 0u;
            if (powner) {
                unsigned pos = (unsigned)((p << 14) | (ex[r8] << 7) | ey[r8]);
                mw |= 0x8000u | (pos & 0x7F78u)
                    | ((unsigned)(((ex[r8] & 1) << 3) | (ey[r8] & 7)) << 16);
            }
            if (psnap) mw |= 0x80000000u | ((unsigned)tvv << 24);
            myent[idx] = make_uint4(mw, __float_as_uint(C), __float_as_uint(Cr), 0u);
        }
        base += (int)__popcll(mask);
    }

    // two pad entries (no-op meta) for the consumer's 2-deep prefetch
    if (lane < 2) myent[base + lane] = make_uint4(0u, 0u, 0u, 0u);
    if (lane == 0) {
        unsigned sm = 0u;
#pragma unroll
        for (int r = 0; r < 8; ++r) if (snl[r] < 0) sm |= 1u << r;
        hdr[wg] = make_uint4((unsigned)base, sm, 0u, 0u);
    }
}

// ---- Kernel B: apply the compacted list to the cell grid ----
__global__ __launch_bounds__(256, 4) void apply_kernel(
    const int*   __restrict__ event,
    const uint4* __restrict__ hdr,
    const uint4* __restrict__ ent,
    float*       __restrict__ out)     // (SN, 8, 2, 64, 64)
{
    const int wg  = blockIdx.x;
    const int s   = wg >> 3;
    const int oct = wg & 7;
    const int p   = oct >> 2;
    const int xc  = oct & 3;
    const int t   = threadIdx.x;

    const uint4  h        = hdr[wg];
    const int    cnt      = (int)h.x;
    const unsigned snapm  = h.y;
    const uint4* e        = ent + (size_t)wg * CAP;

    const int Xl     = t >> 4;
    const int yc     = t & 15;
    const int x_even = xc * 32 + 2 * Xl;
    const unsigned mypatO = (unsigned)((p << 14) | (x_even << 7) | (yc << 3)) | 0x8000u;
    const int X = xc * 16 + Xl;

    float a[16];
#pragma unroll
    for (int j = 0; j < 16; ++j) a[j] = -GMIN;             // v = 0 everywhere

    // init spike at n=0 (C(0)=1)
    bool own0 = false; int j0 = 0;
    {
        const int* ev0 = event + (size_t)s * SPK * 3;
        int x0 = ev0[0], y0 = ev0[1], p0 = ev0[2];
        unsigned pos0 = (unsigned)((p0 << 14) | (x0 << 7) | y0);
        if ((pos0 & 0x7F78u) == (mypatO & 0x7F78u)) {
            own0 = true;
            j0 = ((x0 & 1) << 3) | (y0 & 7);
#pragma unroll
            for (int j = 0; j < 16; ++j)
                if (j == j0) a[j] = PFRAC * (GMAX - GMIN) - GMIN;
        }
    }

    auto step = [&](uint4 cur) {
        unsigned mw = cur.x;
        if (__builtin_expect((mw & 0xFF78u) == mypatO, 0)) {
            float addb = __uint_as_float(cur.z);
            int jidx = (int)((mw >> 16) & 15u);
#pragma unroll
            for (int j = 0; j < 16; ++j)
                a[j] = (j == jidx) ? fmaf(1.0f - PFRAC, a[j], addb) : a[j];
        }
        if (__builtin_expect((int)mw < 0, 0)) {
            int rr = (int)((mw >> 24) & 7u);
            float C = __uint_as_float(cur.y);
            float v[16];
#pragma unroll
            for (int j = 0; j < 16; ++j) v[j] = fmaf(C, a[j], GMIN);
            float4 o;
            o.x = fmaxf(fmaxf(v[0], v[1]), fmaxf(v[8],  v[9]));
            o.y = fmaxf(fmaxf(v[2], v[3]), fmaxf(v[10], v[11]));
            o.z = fmaxf(fmaxf(v[4], v[5]), fmaxf(v[12], v[13]));
            o.w = fmaxf(fmaxf(v[6], v[7]), fmaxf(v[14], v[15]));
            float* dst = out +
                (size_t)((((s * 8 + rr) * 2 + p) * 64 + X) * 64 + yc * 4);
            *reinterpret_cast<float4*>(dst) = o;
        }
    };

    // main loop, 2-deep prefetch (entries + 2 pads exist)
    uint4 c0 = e[0];
    uint4 c1 = e[1];
    for (int i = 0; i < cnt; ++i) {
        uint4 c2 = e[i + 2];
        step(c0);
        c0 = c1;
        c1 = c2;
    }

    // slots that never occur at n>=1: default snapshots
#pragma unroll
    for (int r = 0; r < 8; ++r) {
        if ((snapm >> r) & 1u) {
            float4 o = make_float4(0.f, 0.f, 0.f, 0.f);
            if (r == 0 && own0) {                          // slot 0 keeps init point
                float val = PFRAC * (GMAX - GMIN);
                int k0 = (j0 & 7) >> 1;
                if      (k0 == 0) o.x = val;
                else if (k0 == 1) o.y = val;
                else if (k0 == 2) o.z = val;
                else              o.w = val;
            }
            float* dst = out + (size_t)((((s * 8 + r) * 2 + p) * 64 + X) * 64 + yc * 4);
            *reinterpret_cast<float4*>(dst) = o;
        }
    }
}

extern "C" void kernel_launch(void* const* d_in, const int* in_sizes, int n_in,
                              void* d_out, int out_size, void* d_ws, size_t ws_size,
                              hipStream_t stream) {
    const int*   event  = (const int*)  d_in[0];
    const float* ts     = (const float*)d_in[1];
    const int*   tt     = (const int*)  d_in[2];
    const int*   length = (const int*)  d_in[3];
    float*       out    = (float*)d_out;

    uint4* hdr = (uint4*)d_ws;                 // SN*8 headers = 16 KB
    uint4* ent = hdr + SN * 8;                 // SN*8*CAP entries ~ 8.7 MB

    build_kernel<<<dim3(SN * 8), dim3(64),  0, stream>>>(event, ts, tt, length, hdr, ent);
    apply_kernel<<<dim3(SN * 8), dim3(256), 0, stream>>>(event, hdr, ent, out);
}

// Round 7
// 24.432 us; speedup vs baseline: 1.1801x; 1.1801x over previous
//
#include <hip/hip_runtime.h>

#define SN 128
#define SPK 512

constexpr float GMIN  = 0.1f;
constexpr float PFRAC = 0.3f;
constexpr float GMAX  = 1.0f;

// Wave-synchronous lazy-decay kernel. One 64-lane wave per block; block covers
// a quarter-octant: (sample s, polarity p, x in [xq*8, xq*8+8)), all 128 y.
// Lane: xl = lane>>4 (x-pair), yc = lane&15 (8-wide y chunk); 16 cells/lane:
//   a[j], j = (x&1)<<3 | (y&7);  v = C(n)*a + GMIN,  C(n)=exp((ts0-ts[n])/TAU).
// Spike touch at step n: a' = (1-PFRAC)*a + PFRAC*(GMAX-GMIN)/C(n).
// Per 64-step round: ballot-compact {owner events, surviving snapshots}, then
// scalar-walk the mask broadcasting {meta, C, 0.27/C} via v_readlane (SGPRs).
// No LDS, no barriers, no atomics.
//
// meta: bits 3-14 pos (p<<14|x<<7|y) stripped by 0x7F78 | bit 15 owner-valid |
//       bits 16-19 jidx ((x&1)<<3 | (y&7)) | bits 24-26 snap slot | bit 31 snap.

__global__ __launch_bounds__(64, 4) void trace_kernel(
    const int*   __restrict__ event,   // (SN, SPK, 3) int32: x, y, pol
    const float* __restrict__ ts,      // (SN, SPK) f32, ascending
    const int*   __restrict__ tt,      // (SN, SPK) int32 in [0,8)
    const int*   __restrict__ length,  // (SN,) int32
    float*       __restrict__ out)     // (SN, 8, 2, 64, 64) f32
{
    const int wg   = blockIdx.x;
    const int s    = wg >> 5;
    const int p    = (wg >> 4) & 1;
    const int xq   = wg & 15;
    const int lane = threadIdx.x;      // 0..63

    const int   len = length[s];
    const float ts0 = ts[s * SPK];

    // ---- pass 1: load the full step sequence into registers ----
    int tv[8]; float tsn[8]; int ex[8], ey[8], ep[8];
#pragma unroll
    for (int r8 = 0; r8 < 8; ++r8) {
        int n = r8 * 64 + lane;
        tv[r8]  = tt[s * SPK + n];
        tsn[r8] = ts[s * SPK + n];
        const int* ev = event + (size_t)(s * SPK + n) * 3;
        ex[r8] = ev[0]; ey[r8] = ev[1]; ep[r8] = ev[2];
    }

    // ---- snlast per slot (wave-uniform scalars via ballots) ----
    int snl[8];
#pragma unroll
    for (int r = 0; r < 8; ++r) snl[r] = -1;
#pragma unroll
    for (int r8 = 0; r8 < 8; ++r8) {
        int n = r8 * 64 + lane;
#pragma unroll
        for (int r = 0; r < 8; ++r) {
            unsigned long long m = __ballot(n >= 1 && tv[r8] == r);
            if (m) snl[r] = r8 * 64 + 63 - __clzll(m);
        }
    }

    // ---- per-lane cell block ----
    const int xl     = lane >> 4;
    const int yc     = lane & 15;
    const int x_even = xq * 8 + 2 * xl;
    const unsigned mypatO = (unsigned)((p << 14) | (x_even << 7) | (yc << 3)) | 0x8000u;
    const int Xo = xq * 4 + xl;        // pooled output row

    float a[16];
#pragma unroll
    for (int j = 0; j < 16; ++j) a[j] = -GMIN;             // v = 0 everywhere

    // init spike at n=0 (C(0)=1)
    bool own0 = false; int j0 = 0;
    {
        const int* ev0 = event + (size_t)s * SPK * 3;
        int x0 = ev0[0], y0 = ev0[1], p0 = ev0[2];
        unsigned pos0 = (unsigned)((p0 << 14) | (x0 << 7) | y0);
        if ((pos0 & 0x7F78u) == (mypatO & 0x7F78u)) {
            own0 = true;
            j0 = ((x0 & 1) << 3) | (y0 & 7);
#pragma unroll
            for (int j = 0; j < 16; ++j)
                if (j == j0) a[j] = PFRAC * (GMAX - GMIN) - GMIN;
        }
    }

    // ---- pass 2: fused compaction + apply, 8 rounds of 64 steps ----
#pragma unroll
    for (int r8 = 0; r8 < 8; ++r8) {
        int n   = r8 * 64 + lane;
        int tvv = tv[r8];
        int sl = snl[0];
        sl = (tvv == 1) ? snl[1] : sl;
        sl = (tvv == 2) ? snl[2] : sl;
        sl = (tvv == 3) ? snl[3] : sl;
        sl = (tvv == 4) ? snl[4] : sl;
        sl = (tvv == 5) ? snl[5] : sl;
        sl = (tvv == 6) ? snl[6] : sl;
        sl = (tvv == 7) ? snl[7] : sl;

        bool psnap  = (n >= 1) && (sl == n);
        bool powner = (n >= 1) && (n < len) && (ep[r8] == p) && ((ex[r8] >> 3) == xq);
        bool pred   = powner || psnap;

        unsigned mymw = 0u; float myC = 0.0f, myCr = 0.0f;
        if (pred) {
            myC  = expf((ts0 - tsn[r8]) * 0.01f);                          // TAU=100
            myCr = (PFRAC * (GMAX - GMIN)) * expf((tsn[r8] - ts0) * 0.01f);
            if (powner) {
                unsigned pos = (unsigned)((p << 14) | (ex[r8] << 7) | ey[r8]);
                mymw |= 0x8000u | (pos & 0x7F78u)
                      | ((unsigned)(((ex[r8] & 1) << 3) | (ey[r8] & 7)) << 16);
            }
            if (psnap) mymw |= 0x80000000u | ((unsigned)tvv << 24);
        }

        unsigned long long mask = __ballot(pred);
        while (mask) {
            int src = (int)__builtin_ctzll(mask);
            mask &= mask - 1;
            unsigned mw  = (unsigned)__builtin_amdgcn_readlane((int)mymw, src);
            int      Ci  = __builtin_amdgcn_readlane(__float_as_int(myC),  src);
            int      Cri = __builtin_amdgcn_readlane(__float_as_int(myCr), src);

            if ((mw & 0xFF78u) == mypatO) {            // rare: 1 lane owns spike
                float addb = __int_as_float(Cri);
                int jidx = (int)((mw >> 16) & 15u);
#pragma unroll
                for (int j = 0; j < 16; ++j)
                    a[j] = (j == jidx) ? fmaf(1.0f - PFRAC, a[j], addb) : a[j];
            }
            if ((int)mw < 0) {                         // wave-uniform: snapshot
                int   rr = (int)((mw >> 24) & 7u);
                float C  = __int_as_float(Ci);
                float v[16];
#pragma unroll
                for (int j = 0; j < 16; ++j) v[j] = fmaf(C, a[j], GMIN);
                float4 o;
                o.x = fmaxf(fmaxf(v[0], v[1]), fmaxf(v[8],  v[9]));
                o.y = fmaxf(fmaxf(v[2], v[3]), fmaxf(v[10], v[11]));
                o.z = fmaxf(fmaxf(v[4], v[5]), fmaxf(v[12], v[13]));
                o.w = fmaxf(fmaxf(v[6], v[7]), fmaxf(v[14], v[15]));
                float* dst = out +
                    (size_t)((((s * 8 + rr) * 2 + p) * 64 + Xo) * 64 + yc * 4);
                *reinterpret_cast<float4*>(dst) = o;
            }
        }
    }

    // ---- slots that never occur at n>=1: default snapshots ----
#pragma unroll
    for (int r = 0; r < 8; ++r) {
        if (snl[r] < 0) {
            float4 o = make_float4(0.f, 0.f, 0.f, 0.f);
            if (r == 0 && own0) {                      // slot 0 keeps init point
                float val = PFRAC * (GMAX - GMIN);
                int k0 = (j0 & 7) >> 1;
                if      (k0 == 0) o.x = val;
                else if (k0 == 1) o.y = val;
                else if (k0 == 2) o.z = val;
                else              o.w = val;
            }
            float* dst = out +
                (size_t)((((s * 8 + r) * 2 + p) * 64 + Xo) * 64 + yc * 4);
            *reinterpret_cast<float4*>(dst) = o;
        }
    }
}

extern "C" void kernel_launch(void* const* d_in, const int* in_sizes, int n_in,
                              void* d_out, int out_size, void* d_ws, size_t ws_size,
                              hipStream_t stream) {
    const int*   event  = (const int*)  d_in[0];
    const float* ts     = (const float*)d_in[1];
    const int*   tt     = (const int*)  d_in[2];
    const int*   length = (const int*)  d_in[3];
    float*       out    = (float*)d_out;

    // 128 samples x 2 polarities x 16 x-quarters = 4096 one-wave blocks
    trace_kernel<<<dim3(SN * 2 * 16), dim3(64), 0, stream>>>(event, ts, tt, length, out);
}

// Round 8
// 18.675 us; speedup vs baseline: 1.5440x; 1.3083x over previous
//
#include <hip/hip_runtime.h>

#define SN 128
#define SPK 512

constexpr float GMIN  = 0.1f;
constexpr float PFRAC = 0.3f;
constexpr float GMAX  = 1.0f;

// Wave-synchronous lazy-decay kernel, 32 cells/lane.
// Block = (s, p, xq): polarity plane p of sample s, x in [xq*16, xq*16+16).
// Lane: xp = lane>>3 (x-pair), yb = lane&7 (16-wide y chunk).
// Cells per lane: a[j], j = (x&1)<<4 | (y&15);  v = C(n)*a + GMIN,
//   C(n) = exp((ts0-ts[n])/TAU).  Spike: a' = (1-PFRAC)*a + 0.27/C(n).
// Per 64-step round: ballot-compact {owner events, surviving snapshots},
// scalar-walk the mask broadcasting {meta, C, Cr} via readlane.
// Owner update is branch-free: uniform jidx switch + coef/addb selects.
//
// meta: bits 4-14 pos (p<<14|x<<7|y masked 0x7F70) | bit 15 owner-valid |
//       bits 16-20 jidx | bits 24-26 tt value | bit 31 snapshot flag.

__global__ __launch_bounds__(64, 2) void trace_kernel(
    const int*   __restrict__ event,   // (SN, SPK, 3) int32: x, y, pol
    const float* __restrict__ ts,      // (SN, SPK) f32, ascending
    const int*   __restrict__ tt,      // (SN, SPK) int32 in [0,8)
    const int*   __restrict__ length,  // (SN,) int32
    float*       __restrict__ out)     // (SN, 8, 2, 64, 64) f32
{
    const int wg   = blockIdx.x;
    const int s    = wg >> 4;
    const int p    = (wg >> 3) & 1;
    const int xq   = wg & 7;
    const int lane = threadIdx.x;      // 0..63

    const int   len = length[s];
    const float ts0 = ts[s * SPK];

    // ---- pass 1: load the full step sequence into registers ----
    int tv[8]; float tsn[8]; int ex[8], ey[8], ep[8];
#pragma unroll
    for (int r8 = 0; r8 < 8; ++r8) {
        int n = r8 * 64 + lane;
        tv[r8]  = tt[s * SPK + n];
        tsn[r8] = ts[s * SPK + n];
        const int* ev = event + (size_t)(s * SPK + n) * 3;
        ex[r8] = ev[0]; ey[r8] = ev[1]; ep[r8] = ev[2];
    }

    // ---- snlast per slot (wave-uniform scalars via ballots) ----
    int snl[8];
#pragma unroll
    for (int r = 0; r < 8; ++r) snl[r] = -1;
#pragma unroll
    for (int r8 = 0; r8 < 8; ++r8) {
        int n = r8 * 64 + lane;
#pragma unroll
        for (int r = 0; r < 8; ++r) {
            unsigned long long m = __ballot(n >= 1 && tv[r8] == r);
            if (m) snl[r] = r8 * 64 + 63 - __clzll(m);
        }
    }

    // ---- per-lane cell block ----
    const int xp     = lane >> 3;      // 0..7  x-pair within chunk
    const int yb     = lane & 7;       // 0..7  16-wide y chunk
    const int x_even = xq * 16 + 2 * xp;
    const unsigned mypatO = (unsigned)((p << 14) | (x_even << 7) | (yb << 4)) | 0x8000u;
    const int Xo = xq * 8 + xp;        // pooled output row

    float a[32];
#pragma unroll
    for (int j = 0; j < 32; ++j) a[j] = -GMIN;             // v = 0 everywhere

    // init spike at n=0 (C(0)=1)
    bool own0 = false; int j0 = 0;
    {
        const int* ev0 = event + (size_t)s * SPK * 3;
        int x0 = ev0[0], y0 = ev0[1], p0 = ev0[2];
        unsigned pos0 = (unsigned)((p0 << 14) | (x0 << 7) | y0);
        if ((pos0 & 0x7F70u) == (mypatO & 0x7F70u)) {
            own0 = true;
            j0 = ((x0 & 1) << 4) | (y0 & 15);
#pragma unroll
            for (int j = 0; j < 32; ++j)
                if (j == j0) a[j] = PFRAC * (GMAX - GMIN) - GMIN;
        }
    }

    // ---- fused compaction + apply, 8 rounds of 64 steps ----
#pragma unroll
    for (int r8 = 0; r8 < 8; ++r8) {
        int n = r8 * 64 + lane;

        bool psnap = false;
#pragma unroll
        for (int r = 0; r < 8; ++r) psnap |= (n == snl[r]);
        bool powner = (n >= 1) && (n < len) && (ep[r8] == p) && ((ex[r8] >> 4) == xq);
        bool pred   = powner || psnap;

        unsigned mymw = 0u; float myC = 0.0f, myCr = 0.0f;
        if (pred) {
            float d = (ts0 - tsn[r8]) * 0.01f;             // TAU = 100
            myC  = __expf(d);
            myCr = (PFRAC * (GMAX - GMIN)) * __expf(-d);
            mymw = (unsigned)tv[r8] << 24;
            if (powner) {
                unsigned pos = (unsigned)((p << 14) | (ex[r8] << 7) | ey[r8]);
                mymw |= 0x8000u | (pos & 0x7F70u)
                      | ((unsigned)(((ex[r8] & 1) << 4) | (ey[r8] & 15)) << 16);
            }
            if (psnap) mymw |= 0x80000000u;
        }

        unsigned long long mask = __ballot(pred);
        while (mask) {
            int src = (int)__builtin_ctzll(mask);
            mask &= mask - 1;
            unsigned mw  = (unsigned)__builtin_amdgcn_readlane((int)mymw, src);
            int      Cri = __builtin_amdgcn_readlane(__float_as_int(myCr), src);

            // owner update, branch-free: exactly one lane matches; others
            // apply identity (coef=1, addb=0) to the same uniform register.
            bool  own  = (mw & 0xFF70u) == mypatO;
            float coef = own ? (1.0f - PFRAC) : 1.0f;
            float addb = own ? __int_as_float(Cri) : 0.0f;
            switch ((mw >> 16) & 31u) {
#define OWN_CASE(k) case k: a[k] = fmaf(coef, a[k], addb); break;
                OWN_CASE(0)  OWN_CASE(1)  OWN_CASE(2)  OWN_CASE(3)
                OWN_CASE(4)  OWN_CASE(5)  OWN_CASE(6)  OWN_CASE(7)
                OWN_CASE(8)  OWN_CASE(9)  OWN_CASE(10) OWN_CASE(11)
                OWN_CASE(12) OWN_CASE(13) OWN_CASE(14) OWN_CASE(15)
                OWN_CASE(16) OWN_CASE(17) OWN_CASE(18) OWN_CASE(19)
                OWN_CASE(20) OWN_CASE(21) OWN_CASE(22) OWN_CASE(23)
                OWN_CASE(24) OWN_CASE(25) OWN_CASE(26) OWN_CASE(27)
                OWN_CASE(28) OWN_CASE(29) OWN_CASE(30) OWN_CASE(31)
#undef OWN_CASE
            }

            if ((int)mw < 0) {                             // wave-uniform: snapshot
                int   Ci = __builtin_amdgcn_readlane(__float_as_int(myC), src);
                float C  = __int_as_float(Ci);
                int   rr = (int)((mw >> 24) & 7u);
                float o[8];
#pragma unroll
                for (int k = 0; k < 8; ++k) {
                    float v0 = fmaf(C, a[2 * k],      GMIN);
                    float v1 = fmaf(C, a[2 * k + 1],  GMIN);
                    float v2 = fmaf(C, a[16 + 2 * k], GMIN);
                    float v3 = fmaf(C, a[17 + 2 * k], GMIN);
                    o[k] = fmaxf(fmaxf(v0, v1), fmaxf(v2, v3));
                }
                float* dst = out +
                    (size_t)((((s * 8 + rr) * 2 + p) * 64 + Xo) * 64 + yb * 8);
                *reinterpret_cast<float4*>(dst)     = make_float4(o[0], o[1], o[2], o[3]);
                *reinterpret_cast<float4*>(dst + 4) = make_float4(o[4], o[5], o[6], o[7]);
            }
        }
    }

    // ---- slots that never occur at n>=1: default snapshots ----
#pragma unroll
    for (int r = 0; r < 8; ++r) {
        if (snl[r] < 0) {
            float o[8];
#pragma unroll
            for (int k = 0; k < 8; ++k) {
                bool hit = (r == 0) && own0 && (k == ((j0 & 15) >> 1));
                o[k] = hit ? PFRAC * (GMAX - GMIN) : 0.0f;
            }
            float* dst = out +
                (size_t)((((s * 8 + r) * 2 + p) * 64 + Xo) * 64 + yb * 8);
            *reinterpret_cast<float4*>(dst)     = make_float4(o[0], o[1], o[2], o[3]);
            *reinterpret_cast<float4*>(dst + 4) = make_float4(o[4], o[5], o[6], o[7]);
        }
    }
}

extern "C" void kernel_launch(void* const* d_in, const int* in_sizes, int n_in,
                              void* d_out, int out_size, void* d_ws, size_t ws_size,
                              hipStream_t stream) {
    const int*   event  = (const int*)  d_in[0];
    const float* ts     = (const float*)d_in[1];
    const int*   tt     = (const int*)  d_in[2];
    const int*   length = (const int*)  d_in[3];
    float*       out    = (float*)d_out;

    // 128 samples x 2 polarities x 8 x-chunks = 2048 one-wave blocks
    trace_kernel<<<dim3(SN * 2 * 8), dim3(64), 0, stream>>>(event, ts, tt, length, out);
}